// Round 10
// baseline (8526.124 us; speedup 1.0000x reference)
//
#include <hip/hip_runtime.h>
#include <hip/hip_fp16.h>
#include <math.h>

#define NCH   1024            // 2048 timesteps / CH=2
#define KMAX  1034            // last event: R4 chunk 1023 at k = 1023+10
#define HID   64
typedef unsigned int uint;
typedef __attribute__((ext_vector_type(2))) _Float16 h2t;

__device__ __forceinline__ float sigmoid_(float x){ return 1.0f/(1.0f+__expf(-x)); }
__device__ __forceinline__ float tanh_(float x){ float e=__expf(2.0f*x); return 1.0f-2.0f/(e+1.0f); }

__device__ __forceinline__ float fdot2_(uint w, uint h, float acc){
#if __has_builtin(__builtin_amdgcn_fdot2)
    return __builtin_amdgcn_fdot2(__builtin_bit_cast(h2t,w), __builtin_bit_cast(h2t,h), acc, false);
#else
    __half2 wv = *reinterpret_cast<const __half2*>(&w);
    __half2 hv = *reinterpret_cast<const __half2*>(&h);
    float2 wf = __half22float2(wv), hf = __half22float2(hv);
    return fmaf(wf.x, hf.x, fmaf(wf.y, hf.y, acc));
#endif
}
__device__ __forceinline__ uint packh(float a, float b){
    uint ha = (uint)__half_as_ushort(__float2half(a));   // RNE
    uint hb = (uint)__half_as_ushort(__float2half(b));
    return (hb<<16)|ha;
}
__device__ __forceinline__ uint4 pack8(const float* p){
    return make_uint4(packh(p[0],p[1]), packh(p[2],p[3]), packh(p[4],p[5]), packh(p[6],p[7]));
}

#define DOT4(A, W, H) do{ \
    A=fdot2_((W).x,(H).x,A); A=fdot2_((W).y,(H).y,A); \
    A=fdot2_((W).z,(H).z,A); A=fdot2_((W).w,(H).w,A); }while(0)
#define DOT8(A, W, HH, HL) do{ DOT4(A,W,HH); DOT4(A,W,HL); }while(0)

// All 5 LSTM layers, wavefront-pipelined, ONE kernel.
// grid = 256 blocks (1 sample), block = 256 threads (4 waves; VGPR cap law:
// cap = 65536/block_threads -> 256 here, proven no-spill at 236 in r9).
// CH=2 steps/chunk, 1034 supercycles, one __syncthreads each.
//   w0: recurrence L0+L1 + xg[L4] rows 0-127 (LDS W)
//   w1: recurrence L2+L3 + xg[L4] rows 128-255 (LDS W)
//   w2: recurrence L4 + stage x + xg[L0] (reg W, K=45) + xg[L2] rows 128-255 (LDS W)
//   w3: xg[L1] (reg W) + xg[L2] rows 0-127 (reg W) + xg[L3] (LDS W)
// Round-10: (a) hi/lo compensation split into separate dot chains (2x ILP);
// (b) G blocks d-outer/t-inner -> LDS weight rows read once per supercycle
// (halves G LDS traffic + bank conflicts); (c) unguarded fast path for
// k in [10, NCH) so independent R/G pieces co-schedule.
// Schedule (r9-verified): stage x(c)@k=c; G_l(c)@k=c+1+2l; R_l(c)@k=c+2+2l.
__global__ __attribute__((amdgpu_waves_per_eu(1,1))) __launch_bounds__(256)
void lstm_pipe4(const float* __restrict__ x,          // [256,2048,45]
                const float* __restrict__ W_ih0,      // [256,45]
                const float* __restrict__ W_ih_rest,  // [4,256,64]
                const float* __restrict__ W_hh,       // [5,256,64]
                const float* __restrict__ b_ih,       // [5,256]
                const float* __restrict__ b_hh,       // [5,256]
                float* __restrict__ h_last)           // [256,64] (d_ws)
{
    __shared__ float s_xg[2][5][2][256];        // 20480 B  xg double buffer (fp32)
    __shared__ uint  s_wo [5][8][64][4];        // 40960 B  W_hh o-gate, fp16 packed
    __shared__ uint  s_wih[10][8][64][4];       // 81920 B  W_ih groups, fp16 packed
    __shared__ uint  s_hhhi[4][2][2][32];       //  2048 B  h handoff hi
    __shared__ uint  s_hhlo[4][2][2][32];       //  2048 B  h handoff lo
    __shared__ uint  s_h16hi[5][32];            //   640 B  per-layer running h hi
    __shared__ uint  s_h16lo[5][32];            //   640 B  per-layer running h lo
    __shared__ uint  s_xhi[2][2][24];           //   384 B  staged x hi
    __shared__ uint  s_xlo[2][2][24];           //   384 B  staged x lo
    // total 149504 B -> 1 block/CU

    const int tid  = threadIdx.x;
    const int wave = tid >> 6;
    const int lane = tid & 63;
    const int sm   = blockIdx.x;
    const float* x_s = x + (size_t)sm * 2048 * 45;
    float* hlast_g = h_last + (size_t)sm * HID;

    uint4 wU[48];          // per-wave weight register file (192 dwords), static-indexed
    float b0=0,b1=0,b2=0,b3=0,b4=0,b5=0,b6=0,b7=0,b8=0,b9=0;
    float cA=0.f, cB=0.f;  // cell states

    // ================= init: pack weights, stage LDS (r9-verified) =================
    if (wave == 0 || wave == 1){
#pragma unroll
        for (int li=0; li<2; ++li){
            const int L = wave*2 + li;
            const float* base = W_hh + (size_t)L*256*64;
#pragma unroll
            for (int d=0; d<8; ++d){
                wU[li*24 + 0*8 + d] = pack8(base + (size_t)(  0+lane)*64 + 8*d);  // i
                wU[li*24 + 1*8 + d] = pack8(base + (size_t)( 64+lane)*64 + 8*d);  // f
                wU[li*24 + 2*8 + d] = pack8(base + (size_t)(128+lane)*64 + 8*d);  // g
                *(uint4*)&s_wo[L][d][lane][0] = pack8(base + (size_t)(192+lane)*64 + 8*d); // o
            }
            if (lane<32){ s_h16hi[L][lane]=0u; s_h16lo[L][lane]=0u; }
        }
#pragma unroll
        for (int g=0; g<2; ++g){
            const int row = wave*128 + g*64 + lane;
            const float* src = W_ih_rest + ((size_t)3*256 + row)*64;
            const int grp = 6 + wave*2 + g;
#pragma unroll
            for (int d=0; d<8; ++d)
                *(uint4*)&s_wih[grp][d][lane][0] = pack8(src + 8*d);
        }
        { int r0 = 4*256 + wave*128 + lane, r1 = r0 + 64;
          b0 = b_ih[r0]+b_hh[r0]; b1 = b_ih[r1]+b_hh[r1]; }
    } else if (wave == 2){
        const float* base = W_hh + (size_t)4*256*64;
#pragma unroll
        for (int d=0; d<8; ++d){
            wU[0*8+d] = pack8(base + (size_t)(  0+lane)*64 + 8*d);
            wU[1*8+d] = pack8(base + (size_t)( 64+lane)*64 + 8*d);
            wU[2*8+d] = pack8(base + (size_t)(128+lane)*64 + 8*d);
            *(uint4*)&s_wo[4][d][lane][0] = pack8(base + (size_t)(192+lane)*64 + 8*d);
        }
        if (lane<32){ s_h16hi[4][lane]=0u; s_h16lo[4][lane]=0u; }
#pragma unroll
        for (int g=0; g<4; ++g){
            const float* src = W_ih0 + (size_t)(g*64+lane)*45;
#pragma unroll
            for (int d=0; d<6; ++d){
                float e0=(8*d+0<45)?src[8*d+0]:0.f, e1=(8*d+1<45)?src[8*d+1]:0.f;
                float e2=(8*d+2<45)?src[8*d+2]:0.f, e3=(8*d+3<45)?src[8*d+3]:0.f;
                float e4=(8*d+4<45)?src[8*d+4]:0.f, e5=(8*d+5<45)?src[8*d+5]:0.f;
                float e6=(8*d+6<45)?src[8*d+6]:0.f, e7=(8*d+7<45)?src[8*d+7]:0.f;
                wU[24 + g*6 + d] = make_uint4(packh(e0,e1),packh(e2,e3),packh(e4,e5),packh(e6,e7));
            }
        }
        { int r;
          r=      lane; b0=b_ih[r]+b_hh[r];
          r=  64+lane;  b1=b_ih[r]+b_hh[r];
          r= 128+lane;  b2=b_ih[r]+b_hh[r];
          r= 192+lane;  b3=b_ih[r]+b_hh[r]; }
#pragma unroll
        for (int g=0; g<2; ++g){
            const int row = 128 + g*64 + lane;
            const float* src = W_ih_rest + ((size_t)1*256 + row)*64;
#pragma unroll
            for (int d=0; d<8; ++d)
                *(uint4*)&s_wih[g][d][lane][0] = pack8(src + 8*d);
        }
        { int r0=2*256+128+lane, r1=2*256+192+lane;
          b4=b_ih[r0]+b_hh[r0]; b5=b_ih[r1]+b_hh[r1]; }
        if (lane < 12){
            int bb=lane/6, t=(lane%6)/3, d=45+lane%3;
            ((__half*)&s_xhi[bb][t][0])[d]=__float2half(0.f);
            ((__half*)&s_xlo[bb][t][0])[d]=__float2half(0.f);
        }
    } else { // wave 3
#pragma unroll
        for (int g=0; g<6; ++g){
            const int ly  = (g<4) ? 1 : 2;
            const int row = (g<4) ? g*64+lane : (g-4)*64+lane;
            const float* src = W_ih_rest + ((size_t)(ly-1)*256 + row)*64;
#pragma unroll
            for (int d=0; d<8; ++d) wU[g*8+d] = pack8(src + 8*d);
        }
        { int r;
          r=1*256+  0+lane; b0=b_ih[r]+b_hh[r];
          r=1*256+ 64+lane; b1=b_ih[r]+b_hh[r];
          r=1*256+128+lane; b2=b_ih[r]+b_hh[r];
          r=1*256+192+lane; b3=b_ih[r]+b_hh[r];
          r=2*256+  0+lane; b4=b_ih[r]+b_hh[r];
          r=2*256+ 64+lane; b5=b_ih[r]+b_hh[r]; }
#pragma unroll
        for (int g=0; g<4; ++g){
            const float* src = W_ih_rest + ((size_t)2*256 + g*64+lane)*64;
#pragma unroll
            for (int d=0; d<8; ++d) *(uint4*)&s_wih[2+g][d][lane][0] = pack8(src + 8*d);
        }
        { int r;
          r=3*256+  0+lane; b6=b_ih[r]+b_hh[r];
          r=3*256+ 64+lane; b7=b_ih[r]+b_hh[r];
          r=3*256+128+lane; b8=b_ih[r]+b_hh[r];
          r=3*256+192+lane; b9=b_ih[r]+b_hh[r]; }
    }
    __syncthreads();

// ---- recurrence step, hi/lo-split chains (8 independent dot chains) ----
#define R_STEPF(L, WB, LASTF, T, C, CST) do{                                   \
    const int buf_ = (C)&1;                                                    \
    float xi_ = s_xg[buf_][L][T][      lane];                                  \
    float xf_ = s_xg[buf_][L][T][ 64 + lane];                                  \
    float xgg_= s_xg[buf_][L][T][128 + lane];                                  \
    float xo_ = s_xg[buf_][L][T][192 + lane];                                  \
    float aih=0,ail=0, afh=0,afl=0, agh=0,agl=0, aoh=0,aol=0;                  \
    _Pragma("unroll")                                                          \
    for (int d_=0; d_<8; ++d_){                                                \
        uint4 hh_ = *(const uint4*)&s_h16hi[L][4*d_];                          \
        uint4 hl_ = *(const uint4*)&s_h16lo[L][4*d_];                          \
        uint4 wo_ = *(const uint4*)&s_wo[L][d_][lane][0];                      \
        DOT4(aih, wU[(WB)+d_],    hh_); DOT4(ail, wU[(WB)+d_],    hl_);        \
        DOT4(afh, wU[(WB)+8+d_],  hh_); DOT4(afl, wU[(WB)+8+d_],  hl_);        \
        DOT4(agh, wU[(WB)+16+d_], hh_); DOT4(agl, wU[(WB)+16+d_], hl_);        \
        DOT4(aoh, wo_,            hh_); DOT4(aol, wo_,            hl_);        \
    }                                                                          \
    float I_=sigmoid_(xi_+(aih+ail)), F_=sigmoid_(xf_+(afh+afl));              \
    float G_=tanh_(xgg_+(agh+agl)),   O_=sigmoid_(xo_+(aoh+aol));              \
    CST = fmaf(F_, CST, I_*G_);                                                \
    float h_ = O_*tanh_(CST);                                                  \
    __half hhi_=__float2half(h_);                                              \
    __half hlo_=__float2half(h_-__half2float(hhi_));                           \
    ((__half*)&s_h16hi[L][0])[lane]=hhi_;                                      \
    ((__half*)&s_h16lo[L][0])[lane]=hlo_;                                      \
    if (!(LASTF)){                                                             \
        ((__half*)&s_hhhi[(L)<4?(L):0][buf_][T][0])[lane]=hhi_;                \
        ((__half*)&s_hhlo[(L)<4?(L):0][buf_][T][0])[lane]=hlo_;                \
    } else if ((C)==NCH-1 && (T)==1){ hlast_g[lane]=h_; }                      \
}while(0)

// ---- G blocks, d-outer / t-inner: weights read ONCE, used for both t ----
#define G4T(DMAX, WEXPR, H0HI,H0LO,H1HI,H1LO, XD0, XD1, B0_,B1_,B2_,B3_) do{   \
    float a00=(B0_),a01=(B1_),a02=(B2_),a03=(B3_);                             \
    float a10=(B0_),a11=(B1_),a12=(B2_),a13=(B3_);                             \
    _Pragma("unroll")                                                          \
    for (int d_=0; d_<(DMAX); ++d_){                                           \
        uint4 w0_=WEXPR(0,d_), w1_=WEXPR(1,d_), w2_=WEXPR(2,d_), w3_=WEXPR(3,d_);\
        uint4 h0h_=*(const uint4*)&(H0HI)[4*d_], h0l_=*(const uint4*)&(H0LO)[4*d_];\
        uint4 h1h_=*(const uint4*)&(H1HI)[4*d_], h1l_=*(const uint4*)&(H1LO)[4*d_];\
        DOT8(a00,w0_,h0h_,h0l_); DOT8(a01,w1_,h0h_,h0l_);                      \
        DOT8(a02,w2_,h0h_,h0l_); DOT8(a03,w3_,h0h_,h0l_);                      \
        DOT8(a10,w0_,h1h_,h1l_); DOT8(a11,w1_,h1h_,h1l_);                      \
        DOT8(a12,w2_,h1h_,h1l_); DOT8(a13,w3_,h1h_,h1l_);                      \
    }                                                                          \
    (XD0)[      lane]=a00; (XD0)[ 64+lane]=a01;                                \
    (XD0)[128+lane]=a02;   (XD0)[192+lane]=a03;                                \
    (XD1)[      lane]=a10; (XD1)[ 64+lane]=a11;                                \
    (XD1)[128+lane]=a12;   (XD1)[192+lane]=a13;                                \
}while(0)

#define G2T(DMAX, WEXPR, H0HI,H0LO,H1HI,H1LO, XD0, XD1, ROWOFF, B0_,B1_) do{   \
    float p00=0,q00=0,p01=0,q01=0, p10=0,q10=0,p11=0,q11=0;                    \
    _Pragma("unroll")                                                          \
    for (int d_=0; d_<(DMAX); ++d_){                                           \
        uint4 wa_ = WEXPR(0,d_), wb_ = WEXPR(1,d_);                            \
        uint4 h0h_=*(const uint4*)&(H0HI)[4*d_], h0l_=*(const uint4*)&(H0LO)[4*d_];\
        uint4 h1h_=*(const uint4*)&(H1HI)[4*d_], h1l_=*(const uint4*)&(H1LO)[4*d_];\
        DOT4(p00,wa_,h0h_); DOT4(q00,wa_,h0l_);                                \
        DOT4(p01,wb_,h0h_); DOT4(q01,wb_,h0l_);                                \
        DOT4(p10,wa_,h1h_); DOT4(q10,wa_,h1l_);                                \
        DOT4(p11,wb_,h1h_); DOT4(q11,wb_,h1l_);                                \
    }                                                                          \
    (XD0)[(ROWOFF)+lane]=(B0_)+p00+q00; (XD0)[(ROWOFF)+64+lane]=(B1_)+p01+q01; \
    (XD1)[(ROWOFF)+lane]=(B0_)+p10+q10; (XD1)[(ROWOFF)+64+lane]=(B1_)+p11+q11; \
}while(0)

// ---- slow-path (guarded) originals ----
#define G4(DMAX, WEXPR, HHI, HLO, XDST, B0_,B1_,B2_,B3_) do{                   \
    float a0_=(B0_), a1_=(B1_), a2_=(B2_), a3_=(B3_);                          \
    _Pragma("unroll")                                                          \
    for (int d_=0; d_<(DMAX); ++d_){                                           \
        uint4 hh_ = *(const uint4*)&(HHI)[4*d_];                               \
        uint4 hl_ = *(const uint4*)&(HLO)[4*d_];                               \
        uint4 wa_ = WEXPR(0,d_); DOT8(a0_, wa_, hh_, hl_);                     \
        uint4 wb_ = WEXPR(1,d_); DOT8(a1_, wb_, hh_, hl_);                     \
        uint4 wc_ = WEXPR(2,d_); DOT8(a2_, wc_, hh_, hl_);                     \
        uint4 wd_ = WEXPR(3,d_); DOT8(a3_, wd_, hh_, hl_);                     \
    }                                                                          \
    (XDST)[      lane]=a0_; (XDST)[ 64+lane]=a1_;                              \
    (XDST)[128+lane]=a2_;   (XDST)[192+lane]=a3_;                              \
}while(0)

#define G2(DMAX, WEXPR, HHI, HLO, XDST, ROWOFF, B0_,B1_) do{                   \
    float a0_=(B0_), a1_=(B1_);                                                \
    _Pragma("unroll")                                                          \
    for (int d_=0; d_<(DMAX); ++d_){                                           \
        uint4 hh_ = *(const uint4*)&(HHI)[4*d_];                               \
        uint4 hl_ = *(const uint4*)&(HLO)[4*d_];                               \
        uint4 wa_ = WEXPR(0,d_); DOT8(a0_, wa_, hh_, hl_);                     \
        uint4 wb_ = WEXPR(1,d_); DOT8(a1_, wb_, hh_, hl_);                     \
    }                                                                          \
    (XDST)[(ROWOFF)+lane]=a0_; (XDST)[(ROWOFF)+64+lane]=a1_;                   \
}while(0)

// weight selectors
#define W_L1(g,d)  wU[(g)*8+(d)]
#define W_L2R(g,d) wU[32+(g)*8+(d)]
#define W_L0(g,d)  wU[24+(g)*6+(d)]
#define W_L2L(g,d) (*(const uint4*)&s_wih[(g)][d][lane][0])
#define W_L3(g,d)  (*(const uint4*)&s_wih[2+(g)][d][lane][0])
#define W_L3A(g,d) (*(const uint4*)&s_wih[2+(g)][d][lane][0])
#define W_L3B(g,d) (*(const uint4*)&s_wih[4+(g)][d][lane][0])
#define W_L4A(g,d) (*(const uint4*)&s_wih[6+(g)][d][lane][0])
#define W_L4B(g,d) (*(const uint4*)&s_wih[8+(g)][d][lane][0])

#define STAGE_X() do{                                                          \
    const int bufx = k & 1;                                                    \
    _Pragma("unroll")                                                          \
    for (int r=0; r<2; ++r){                                                   \
        const int i = lane + 64*r;                                             \
        if (i < 90){                                                           \
            float v = x_s[(size_t)k*90 + i];                                   \
            __half vh = __float2half(v);                                       \
            __half vl = __float2half(v - __half2float(vh));                    \
            const int t = i/45, d = i - 45*t;                                  \
            ((__half*)&s_xhi[bufx][t][0])[d] = vh;                             \
            ((__half*)&s_xlo[bufx][t][0])[d] = vl;                             \
        }                                                                      \
    }                                                                          \
}while(0)

    // ================= supercycle loop =================
    for (int k=0; k<KMAX; ++k){
        if (k >= 10 && k < NCH){
            // ---------- FAST PATH: all pieces valid, no guards ----------
            const int pb  = k & 1;        // buf for R-chunks (c = k - even)
            const int pb1 = pb ^ 1;       // buf for G-chunks (c = k - odd)
            if (wave == 0){
                const int c0=k-2, c1=k-4;
                R_STEPF(0,  0, 0, 0, c0, cA);
                R_STEPF(1, 24, 0, 0, c1, cB);
                R_STEPF(0,  0, 0, 1, c0, cA);
                R_STEPF(1, 24, 0, 1, c1, cB);
                G2T(8, W_L4A, s_hhhi[3][pb1][0], s_hhlo[3][pb1][0],
                              s_hhhi[3][pb1][1], s_hhlo[3][pb1][1],
                    (&s_xg[pb1][4][0][0]), (&s_xg[pb1][4][1][0]), 0, b0,b1);
            } else if (wave == 1){
                const int c2=k-6, c3=k-8;
                R_STEPF(2,  0, 0, 0, c2, cA);
                R_STEPF(3, 24, 0, 0, c3, cB);
                R_STEPF(2,  0, 0, 1, c2, cA);
                R_STEPF(3, 24, 0, 1, c3, cB);
                G2T(8, W_L4B, s_hhhi[3][pb1][0], s_hhlo[3][pb1][0],
                              s_hhhi[3][pb1][1], s_hhlo[3][pb1][1],
                    (&s_xg[pb1][4][0][0]), (&s_xg[pb1][4][1][0]), 128, b0,b1);
            } else if (wave == 2){
                STAGE_X();
                const int c4=k-10;
                R_STEPF(4, 0, 1, 0, c4, cA);
                G4T(6, W_L0, (&s_xhi[pb1][0][0]), (&s_xlo[pb1][0][0]),
                             (&s_xhi[pb1][1][0]), (&s_xlo[pb1][1][0]),
                    (&s_xg[pb1][0][0][0]), (&s_xg[pb1][0][1][0]), b0,b1,b2,b3);
                R_STEPF(4, 0, 1, 1, c4, cA);
                G2T(8, W_L2L, s_hhhi[1][pb1][0], s_hhlo[1][pb1][0],
                              s_hhhi[1][pb1][1], s_hhlo[1][pb1][1],
                    (&s_xg[pb1][2][0][0]), (&s_xg[pb1][2][1][0]), 128, b4,b5);
            } else {
                G4T(8, W_L1, s_hhhi[0][pb1][0], s_hhlo[0][pb1][0],
                             s_hhhi[0][pb1][1], s_hhlo[0][pb1][1],
                    (&s_xg[pb1][1][0][0]), (&s_xg[pb1][1][1][0]), b0,b1,b2,b3);
                G2T(8, W_L2R, s_hhhi[1][pb1][0], s_hhlo[1][pb1][0],
                              s_hhhi[1][pb1][1], s_hhlo[1][pb1][1],
                    (&s_xg[pb1][2][0][0]), (&s_xg[pb1][2][1][0]), 0, b4,b5);
                G2T(8, W_L3A, s_hhhi[2][pb1][0], s_hhlo[2][pb1][0],
                              s_hhhi[2][pb1][1], s_hhlo[2][pb1][1],
                    (&s_xg[pb1][3][0][0]), (&s_xg[pb1][3][1][0]), 0, b6,b7);
                G2T(8, W_L3B, s_hhhi[2][pb1][0], s_hhlo[2][pb1][0],
                              s_hhhi[2][pb1][1], s_hhlo[2][pb1][1],
                    (&s_xg[pb1][3][0][0]), (&s_xg[pb1][3][1][0]), 128, b8,b9);
            }
        } else {
            // ---------- SLOW PATH: prologue/epilogue, guarded ----------
            if (wave == 0){
                const int c0=k-2, c1=k-4, cl=k-9;
                if (c0>=0 && c0<NCH) R_STEPF(0,  0, 0, 0, c0, cA);
                if (c1>=0 && c1<NCH) R_STEPF(1, 24, 0, 0, c1, cB);
                if (c0>=0 && c0<NCH) R_STEPF(0,  0, 0, 1, c0, cA);
                if (c1>=0 && c1<NCH) R_STEPF(1, 24, 0, 1, c1, cB);
                if (cl>=0 && cl<NCH){
                    const int bl=cl&1;
                    G2(8, W_L4A, (&s_hhhi[3][bl][0][0]), (&s_hhlo[3][bl][0][0]), (&s_xg[bl][4][0][0]), 0, b0,b1);
                    G2(8, W_L4A, (&s_hhhi[3][bl][1][0]), (&s_hhlo[3][bl][1][0]), (&s_xg[bl][4][1][0]), 0, b0,b1);
                }
            } else if (wave == 1){
                const int c2=k-6, c3=k-8, cl=k-9;
                if (c2>=0 && c2<NCH) R_STEPF(2,  0, 0, 0, c2, cA);
                if (c3>=0 && c3<NCH) R_STEPF(3, 24, 0, 0, c3, cB);
                if (c2>=0 && c2<NCH) R_STEPF(2,  0, 0, 1, c2, cA);
                if (c3>=0 && c3<NCH) R_STEPF(3, 24, 0, 1, c3, cB);
                if (cl>=0 && cl<NCH){
                    const int bl=cl&1;
                    G2(8, W_L4B, (&s_hhhi[3][bl][0][0]), (&s_hhlo[3][bl][0][0]), (&s_xg[bl][4][0][0]), 128, b0,b1);
                    G2(8, W_L4B, (&s_hhhi[3][bl][1][0]), (&s_hhlo[3][bl][1][0]), (&s_xg[bl][4][1][0]), 128, b0,b1);
                }
            } else if (wave == 2){
                if (k < NCH) STAGE_X();
                const int c4=k-10, cg0=k-1, cg2=k-5;
                if (c4>=0 && c4<NCH)  R_STEPF(4, 0, 1, 0, c4, cA);
                if (cg0>=0 && cg0<NCH){
                    const int bg=cg0&1;
                    G4(6, W_L0, (&s_xhi[bg][0][0]), (&s_xlo[bg][0][0]), (&s_xg[bg][0][0][0]), b0,b1,b2,b3);
                    G4(6, W_L0, (&s_xhi[bg][1][0]), (&s_xlo[bg][1][0]), (&s_xg[bg][0][1][0]), b0,b1,b2,b3);
                }
                if (c4>=0 && c4<NCH)  R_STEPF(4, 0, 1, 1, c4, cA);
                if (cg2>=0 && cg2<NCH){
                    const int bg=cg2&1;
                    G2(8, W_L2L, (&s_hhhi[1][bg][0][0]), (&s_hhlo[1][bg][0][0]), (&s_xg[bg][2][0][0]), 128, b4,b5);
                    G2(8, W_L2L, (&s_hhhi[1][bg][1][0]), (&s_hhlo[1][bg][1][0]), (&s_xg[bg][2][1][0]), 128, b4,b5);
                }
            } else {
                const int cg1=k-3, cg2=k-5, cg3=k-7;
                if (cg1>=0 && cg1<NCH){
                    const int bg=cg1&1;
                    G4(8, W_L1, (&s_hhhi[0][bg][0][0]), (&s_hhlo[0][bg][0][0]), (&s_xg[bg][1][0][0]), b0,b1,b2,b3);
                    G4(8, W_L1, (&s_hhhi[0][bg][1][0]), (&s_hhlo[0][bg][1][0]), (&s_xg[bg][1][1][0]), b0,b1,b2,b3);
                }
                if (cg2>=0 && cg2<NCH){
                    const int bg=cg2&1;
                    G2(8, W_L2R, (&s_hhhi[1][bg][0][0]), (&s_hhlo[1][bg][0][0]), (&s_xg[bg][2][0][0]), 0, b4,b5);
                    G2(8, W_L2R, (&s_hhhi[1][bg][1][0]), (&s_hhlo[1][bg][1][0]), (&s_xg[bg][2][1][0]), 0, b4,b5);
                }
                if (cg3>=0 && cg3<NCH){
                    const int bg=cg3&1;
                    G4(8, W_L3, (&s_hhhi[2][bg][0][0]), (&s_hhlo[2][bg][0][0]), (&s_xg[bg][3][0][0]), b6,b7,b8,b9);
                    G4(8, W_L3, (&s_hhhi[2][bg][1][0]), (&s_hhlo[2][bg][1][0]), (&s_xg[bg][3][1][0]), b6,b7,b8,b9);
                }
            }
        }
        __syncthreads();
    }
}

// MLP head: features = gelu(last @ Wl^T + bl); out = relu(features @ Wo^T + bo)
// d_out layout: out[256*4] first, then features[256*128].
__global__ __launch_bounds__(128)
void head_kernel(const float* __restrict__ h_last,  // [256, 64]
                 const float* __restrict__ Wl,      // [128, 64]
                 const float* __restrict__ bl,      // [128]
                 const float* __restrict__ Wo,      // [4, 128]
                 const float* __restrict__ bo,      // [4]
                 float* __restrict__ d_out)
{
    __shared__ float s_last[HID];
    __shared__ float s_feat[128];
    const int s = blockIdx.x;
    const int j = threadIdx.x;

    if (j < HID) s_last[j] = h_last[(size_t)s * HID + j];
    __syncthreads();

    float acc = bl[j];
#pragma unroll
    for (int k = 0; k < HID; ++k)
        acc = fmaf(s_last[k], Wl[j * HID + k], acc);
    float f = 0.5f * acc * (1.0f + erff(acc * 0.70710678118654752440f));
    d_out[256 * 4 + s * 128 + j] = f;
    s_feat[j] = f;
    __syncthreads();

    if (j < 4) {
        float a = bo[j];
#pragma unroll
        for (int k = 0; k < 128; ++k)
            a = fmaf(s_feat[k], Wo[j * 128 + k], a);
        d_out[s * 4 + j] = fmaxf(a, 0.0f);
    }
}

extern "C" void kernel_launch(void* const* d_in, const int* in_sizes, int n_in,
                              void* d_out, int out_size, void* d_ws, size_t ws_size,
                              hipStream_t stream)
{
    const float* x         = (const float*)d_in[0];  // [256, 2048, 45]
    const float* W_ih0     = (const float*)d_in[1];  // [256, 45]
    const float* W_ih_rest = (const float*)d_in[2];  // [4, 256, 64]
    const float* W_hh      = (const float*)d_in[3];  // [5, 256, 64]
    const float* b_ih      = (const float*)d_in[4];  // [5, 256]
    const float* b_hh      = (const float*)d_in[5];  // [5, 256]
    const float* Wl        = (const float*)d_in[6];  // [128, 64]
    const float* bl        = (const float*)d_in[7];  // [128]
    const float* Wo        = (const float*)d_in[8];  // [4, 128]
    const float* bo        = (const float*)d_in[9];  // [4]

    float* h_last = (float*)d_ws;   // [256, 64] fp32

    lstm_pipe4<<<256, 256, 0, stream>>>(
        x, W_ih0, W_ih_rest, W_hh, b_ih, b_hh, h_last);
    head_kernel<<<256, 128, 0, stream>>>(h_last, Wl, bl, Wo, bo, (float*)d_out);
}

// Round 11
// 4620.570 us; speedup vs baseline: 1.8453x; 1.8453x over previous
//
#include <hip/hip_runtime.h>
#include <hip/hip_fp16.h>
#include <math.h>

#define NCH   1024            // 2048 timesteps / CH=2
#define KMAX  1034            // last event: R4 chunk 1023 at k = 1023+10
#define HID   64
typedef unsigned int uint;
typedef __attribute__((ext_vector_type(2))) _Float16 h2t;

__device__ __forceinline__ float sigmoid_(float x){ return 1.0f/(1.0f+__expf(-x)); }
__device__ __forceinline__ float tanh_(float x){ float e=__expf(2.0f*x); return 1.0f-2.0f/(e+1.0f); }

__device__ __forceinline__ float fdot2_(uint w, uint h, float acc){
#if __has_builtin(__builtin_amdgcn_fdot2)
    return __builtin_amdgcn_fdot2(__builtin_bit_cast(h2t,w), __builtin_bit_cast(h2t,h), acc, false);
#else
    __half2 wv = *reinterpret_cast<const __half2*>(&w);
    __half2 hv = *reinterpret_cast<const __half2*>(&h);
    float2 wf = __half22float2(wv), hf = __half22float2(hv);
    return fmaf(wf.x, hf.x, fmaf(wf.y, hf.y, acc));
#endif
}
__device__ __forceinline__ uint packh(float a, float b){
    uint ha = (uint)__half_as_ushort(__float2half(a));   // RNE
    uint hb = (uint)__half_as_ushort(__float2half(b));
    return (hb<<16)|ha;
}
__device__ __forceinline__ uint4 pack8(const float* p){
    return make_uint4(packh(p[0],p[1]), packh(p[2],p[3]), packh(p[4],p[5]), packh(p[6],p[7]));
}

#define DOT4(A, W, H) do{ \
    A=fdot2_((W).x,(H).x,A); A=fdot2_((W).y,(H).y,A); \
    A=fdot2_((W).z,(H).z,A); A=fdot2_((W).w,(H).w,A); }while(0)

// All 5 LSTM layers, wavefront-pipelined, ONE kernel.
// grid = 256 blocks (1 sample), block = 256 threads (4 waves; VGPR cap law
// cap = 65536/block_threads -> 256; r9 proved 236 no-spill, r10 proved 256 = spill).
// CH=2 steps/chunk, 1034 supercycles, one __syncthreads each.
//   w0: recurrence L0+L1 + xg[L4] rows 0-127 (LDS W)
//   w1: recurrence L2+L3 + xg[L4] rows 128-255 (LDS W)
//   w2: recurrence L4 + stage x + xg[L0] (reg W, K=45) + xg[L2] rows 128-255 (LDS W)
//   w3: xg[L1] (reg W) + xg[L2] rows 0-127 (reg W) + xg[L3] (LDS W)
// Round-11: hi/lo compensation DROPPED (h stored plain fp16) -> halves all
// fdot2 (critical wave 1280->640 per supercycle). Error budget: fp16 weight
// rounding (already present, 1.22e-4 measured) + similar-magnitude h rounding
// -> est 2-4e-4 < 5.66e-4 threshold. G blocks d-outer/t-inner (register-lean
// no-lo variants, ~30 live temps) halve LDS weight reads. Fast path without
// guards for k in [10, NCH).
// Schedule (r9/r10-verified): stage x(c)@k=c; G_l(c)@k=c+1+2l; R_l(c)@k=c+2+2l.
__global__ __attribute__((amdgpu_waves_per_eu(1,1))) __launch_bounds__(256)
void lstm_pipe4(const float* __restrict__ x,          // [256,2048,45]
                const float* __restrict__ W_ih0,      // [256,45]
                const float* __restrict__ W_ih_rest,  // [4,256,64]
                const float* __restrict__ W_hh,       // [5,256,64]
                const float* __restrict__ b_ih,       // [5,256]
                const float* __restrict__ b_hh,       // [5,256]
                float* __restrict__ h_last)           // [256,64] (d_ws)
{
    __shared__ float s_xg[2][5][2][256];        // 20480 B  xg double buffer (fp32)
    __shared__ uint  s_wo [5][8][64][4];        // 40960 B  W_hh o-gate, fp16 packed
    __shared__ uint  s_wih[10][8][64][4];       // 81920 B  W_ih groups, fp16 packed
    __shared__ uint  s_hh[4][2][2][32];         //  2048 B  h handoff (fp16)
    __shared__ uint  s_h16[5][32];              //   640 B  per-layer running h (fp16)
    __shared__ uint  s_x[2][2][24];             //   384 B  staged x chunk (fp16, 45+3 pad)
    // total 146432 B -> 1 block/CU

    const int tid  = threadIdx.x;
    const int wave = tid >> 6;
    const int lane = tid & 63;
    const int sm   = blockIdx.x;
    const float* x_s = x + (size_t)sm * 2048 * 45;
    float* hlast_g = h_last + (size_t)sm * HID;

    uint4 wU[48];          // per-wave weight register file (192 dwords), static-indexed
    float b0=0,b1=0,b2=0,b3=0,b4=0,b5=0,b6=0,b7=0,b8=0,b9=0;
    float cA=0.f, cB=0.f;  // cell states

    // ================= init: pack weights, stage LDS (r9-verified) =================
    if (wave == 0 || wave == 1){
#pragma unroll
        for (int li=0; li<2; ++li){
            const int L = wave*2 + li;
            const float* base = W_hh + (size_t)L*256*64;
#pragma unroll
            for (int d=0; d<8; ++d){
                wU[li*24 + 0*8 + d] = pack8(base + (size_t)(  0+lane)*64 + 8*d);  // i
                wU[li*24 + 1*8 + d] = pack8(base + (size_t)( 64+lane)*64 + 8*d);  // f
                wU[li*24 + 2*8 + d] = pack8(base + (size_t)(128+lane)*64 + 8*d);  // g
                *(uint4*)&s_wo[L][d][lane][0] = pack8(base + (size_t)(192+lane)*64 + 8*d); // o
            }
            if (lane<32) s_h16[L][lane]=0u;
        }
#pragma unroll
        for (int g=0; g<2; ++g){
            const int row = wave*128 + g*64 + lane;
            const float* src = W_ih_rest + ((size_t)3*256 + row)*64;
            const int grp = 6 + wave*2 + g;
#pragma unroll
            for (int d=0; d<8; ++d)
                *(uint4*)&s_wih[grp][d][lane][0] = pack8(src + 8*d);
        }
        { int r0 = 4*256 + wave*128 + lane, r1 = r0 + 64;
          b0 = b_ih[r0]+b_hh[r0]; b1 = b_ih[r1]+b_hh[r1]; }
    } else if (wave == 2){
        const float* base = W_hh + (size_t)4*256*64;
#pragma unroll
        for (int d=0; d<8; ++d){
            wU[0*8+d] = pack8(base + (size_t)(  0+lane)*64 + 8*d);
            wU[1*8+d] = pack8(base + (size_t)( 64+lane)*64 + 8*d);
            wU[2*8+d] = pack8(base + (size_t)(128+lane)*64 + 8*d);
            *(uint4*)&s_wo[4][d][lane][0] = pack8(base + (size_t)(192+lane)*64 + 8*d);
        }
        if (lane<32) s_h16[4][lane]=0u;
#pragma unroll
        for (int g=0; g<4; ++g){
            const float* src = W_ih0 + (size_t)(g*64+lane)*45;
#pragma unroll
            for (int d=0; d<6; ++d){
                float e0=(8*d+0<45)?src[8*d+0]:0.f, e1=(8*d+1<45)?src[8*d+1]:0.f;
                float e2=(8*d+2<45)?src[8*d+2]:0.f, e3=(8*d+3<45)?src[8*d+3]:0.f;
                float e4=(8*d+4<45)?src[8*d+4]:0.f, e5=(8*d+5<45)?src[8*d+5]:0.f;
                float e6=(8*d+6<45)?src[8*d+6]:0.f, e7=(8*d+7<45)?src[8*d+7]:0.f;
                wU[24 + g*6 + d] = make_uint4(packh(e0,e1),packh(e2,e3),packh(e4,e5),packh(e6,e7));
            }
        }
        { int r;
          r=      lane; b0=b_ih[r]+b_hh[r];
          r=  64+lane;  b1=b_ih[r]+b_hh[r];
          r= 128+lane;  b2=b_ih[r]+b_hh[r];
          r= 192+lane;  b3=b_ih[r]+b_hh[r]; }
#pragma unroll
        for (int g=0; g<2; ++g){
            const int row = 128 + g*64 + lane;
            const float* src = W_ih_rest + ((size_t)1*256 + row)*64;
#pragma unroll
            for (int d=0; d<8; ++d)
                *(uint4*)&s_wih[g][d][lane][0] = pack8(src + 8*d);
        }
        { int r0=2*256+128+lane, r1=2*256+192+lane;
          b4=b_ih[r0]+b_hh[r0]; b5=b_ih[r1]+b_hh[r1]; }
        if (lane < 12){
            int bb=lane/6, t=(lane%6)/3, d=45+lane%3;
            ((__half*)&s_x[bb][t][0])[d]=__float2half(0.f);
        }
    } else { // wave 3
#pragma unroll
        for (int g=0; g<6; ++g){
            const int ly  = (g<4) ? 1 : 2;
            const int row = (g<4) ? g*64+lane : (g-4)*64+lane;
            const float* src = W_ih_rest + ((size_t)(ly-1)*256 + row)*64;
#pragma unroll
            for (int d=0; d<8; ++d) wU[g*8+d] = pack8(src + 8*d);
        }
        { int r;
          r=1*256+  0+lane; b0=b_ih[r]+b_hh[r];
          r=1*256+ 64+lane; b1=b_ih[r]+b_hh[r];
          r=1*256+128+lane; b2=b_ih[r]+b_hh[r];
          r=1*256+192+lane; b3=b_ih[r]+b_hh[r];
          r=2*256+  0+lane; b4=b_ih[r]+b_hh[r];
          r=2*256+ 64+lane; b5=b_ih[r]+b_hh[r]; }
#pragma unroll
        for (int g=0; g<4; ++g){
            const float* src = W_ih_rest + ((size_t)2*256 + g*64+lane)*64;
#pragma unroll
            for (int d=0; d<8; ++d) *(uint4*)&s_wih[2+g][d][lane][0] = pack8(src + 8*d);
        }
        { int r;
          r=3*256+  0+lane; b6=b_ih[r]+b_hh[r];
          r=3*256+ 64+lane; b7=b_ih[r]+b_hh[r];
          r=3*256+128+lane; b8=b_ih[r]+b_hh[r];
          r=3*256+192+lane; b9=b_ih[r]+b_hh[r]; }
    }
    __syncthreads();

// ---- recurrence step, no-lo, even/odd-d split chains (8 chains, 16-deep) ----
#define R_STEPN(L, WB, LASTF, T, C, CST) do{                                   \
    const int buf_ = (C)&1;                                                    \
    float xi_ = s_xg[buf_][L][T][      lane];                                  \
    float xf_ = s_xg[buf_][L][T][ 64 + lane];                                  \
    float xgg_= s_xg[buf_][L][T][128 + lane];                                  \
    float xo_ = s_xg[buf_][L][T][192 + lane];                                  \
    float ai0=0,ai1=0, af0=0,af1=0, ag0=0,ag1=0, ao0=0,ao1=0;                  \
    _Pragma("unroll")                                                          \
    for (int d_=0; d_<8; d_+=2){                                               \
        uint4 h0_ = *(const uint4*)&s_h16[L][4*d_];                            \
        uint4 h1_ = *(const uint4*)&s_h16[L][4*d_+4];                          \
        uint4 woA_ = *(const uint4*)&s_wo[L][d_  ][lane][0];                   \
        uint4 woB_ = *(const uint4*)&s_wo[L][d_+1][lane][0];                   \
        DOT4(ai0, wU[(WB)+d_],      h0_); DOT4(ai1, wU[(WB)+d_+1],    h1_);    \
        DOT4(af0, wU[(WB)+8+d_],    h0_); DOT4(af1, wU[(WB)+8+d_+1],  h1_);    \
        DOT4(ag0, wU[(WB)+16+d_],   h0_); DOT4(ag1, wU[(WB)+16+d_+1], h1_);    \
        DOT4(ao0, woA_,             h0_); DOT4(ao1, woB_,             h1_);    \
    }                                                                          \
    float I_=sigmoid_(xi_+(ai0+ai1)), F_=sigmoid_(xf_+(af0+af1));              \
    float G_=tanh_(xgg_+(ag0+ag1)),   O_=sigmoid_(xo_+(ao0+ao1));              \
    CST = fmaf(F_, CST, I_*G_);                                                \
    float h_ = O_*tanh_(CST);                                                  \
    __half hhi_=__float2half(h_);                                              \
    ((__half*)&s_h16[L][0])[lane]=hhi_;                                        \
    if (!(LASTF)){                                                             \
        ((__half*)&s_hh[(L)<4?(L):0][buf_][T][0])[lane]=hhi_;                  \
    } else if ((C)==NCH-1 && (T)==1){ hlast_g[lane]=h_; }                      \
}while(0)

// ---- G blocks, no-lo, d-outer / t-inner: weights read ONCE per supercycle ----
#define G4T(DMAX, WEXPR, H0, H1, XD0, XD1, B0_,B1_,B2_,B3_) do{                \
    float a00=(B0_),a01=(B1_),a02=(B2_),a03=(B3_);                             \
    float a10=(B0_),a11=(B1_),a12=(B2_),a13=(B3_);                             \
    _Pragma("unroll")                                                          \
    for (int d_=0; d_<(DMAX); ++d_){                                           \
        uint4 w0_=WEXPR(0,d_), w1_=WEXPR(1,d_), w2_=WEXPR(2,d_), w3_=WEXPR(3,d_);\
        uint4 h0_=*(const uint4*)&(H0)[4*d_];                                  \
        uint4 h1_=*(const uint4*)&(H1)[4*d_];                                  \
        DOT4(a00,w0_,h0_); DOT4(a01,w1_,h0_); DOT4(a02,w2_,h0_); DOT4(a03,w3_,h0_);\
        DOT4(a10,w0_,h1_); DOT4(a11,w1_,h1_); DOT4(a12,w2_,h1_); DOT4(a13,w3_,h1_);\
    }                                                                          \
    (XD0)[      lane]=a00; (XD0)[ 64+lane]=a01;                                \
    (XD0)[128+lane]=a02;   (XD0)[192+lane]=a03;                                \
    (XD1)[      lane]=a10; (XD1)[ 64+lane]=a11;                                \
    (XD1)[128+lane]=a12;   (XD1)[192+lane]=a13;                                \
}while(0)

#define G2T(DMAX, WEXPR, H0, H1, XD0, XD1, ROWOFF, B0_,B1_) do{                \
    float a00=(B0_),a01=(B1_), a10=(B0_),a11=(B1_);                            \
    _Pragma("unroll")                                                          \
    for (int d_=0; d_<(DMAX); ++d_){                                           \
        uint4 wa_ = WEXPR(0,d_), wb_ = WEXPR(1,d_);                            \
        uint4 h0_=*(const uint4*)&(H0)[4*d_];                                  \
        uint4 h1_=*(const uint4*)&(H1)[4*d_];                                  \
        DOT4(a00,wa_,h0_); DOT4(a01,wb_,h0_);                                  \
        DOT4(a10,wa_,h1_); DOT4(a11,wb_,h1_);                                  \
    }                                                                          \
    (XD0)[(ROWOFF)+lane]=a00; (XD0)[(ROWOFF)+64+lane]=a01;                     \
    (XD1)[(ROWOFF)+lane]=a10; (XD1)[(ROWOFF)+64+lane]=a11;                     \
}while(0)

// weight selectors
#define W_L1(g,d)  wU[(g)*8+(d)]
#define W_L2R(g,d) wU[32+(g)*8+(d)]
#define W_L0(g,d)  wU[24+(g)*6+(d)]
#define W_L2L(g,d) (*(const uint4*)&s_wih[(g)][d][lane][0])
#define W_L3(g,d)  (*(const uint4*)&s_wih[2+(g)][d][lane][0])
#define W_L4A(g,d) (*(const uint4*)&s_wih[6+(g)][d][lane][0])
#define W_L4B(g,d) (*(const uint4*)&s_wih[8+(g)][d][lane][0])

#define STAGE_X() do{                                                          \
    const int bufx = k & 1;                                                    \
    _Pragma("unroll")                                                          \
    for (int r=0; r<2; ++r){                                                   \
        const int i = lane + 64*r;                                             \
        if (i < 90){                                                           \
            float v = x_s[(size_t)k*90 + i];                                   \
            const int t = i/45, d = i - 45*t;                                  \
            ((__half*)&s_x[bufx][t][0])[d] = __float2half(v);                  \
        }                                                                      \
    }                                                                          \
}while(0)

// per-wave supercycle bodies (shared by fast/slow path; guards only in slow)
#define BODY_W0(GUARDED) do{                                                   \
    const int c0=k-2, c1=k-4, cl=k-9;                                          \
    if (!(GUARDED) || (c0>=0 && c0<NCH)){                                      \
        R_STEPN(0,  0, 0, 0, c0, cA); }                                        \
    if (!(GUARDED) || (c1>=0 && c1<NCH)){                                      \
        R_STEPN(1, 24, 0, 0, c1, cB); }                                        \
    if (!(GUARDED) || (c0>=0 && c0<NCH)){                                      \
        R_STEPN(0,  0, 0, 1, c0, cA); }                                        \
    if (!(GUARDED) || (c1>=0 && c1<NCH)){                                      \
        R_STEPN(1, 24, 0, 1, c1, cB); }                                        \
    if (!(GUARDED) || (cl>=0 && cl<NCH)){                                      \
        const int bl=cl&1;                                                     \
        G2T(8, W_L4A, (&s_hh[3][bl][0][0]), (&s_hh[3][bl][1][0]),              \
            (&s_xg[bl][4][0][0]), (&s_xg[bl][4][1][0]), 0, b0,b1); }           \
}while(0)

#define BODY_W1(GUARDED) do{                                                   \
    const int c2=k-6, c3=k-8, cl=k-9;                                          \
    if (!(GUARDED) || (c2>=0 && c2<NCH)){                                      \
        R_STEPN(2,  0, 0, 0, c2, cA); }                                        \
    if (!(GUARDED) || (c3>=0 && c3<NCH)){                                      \
        R_STEPN(3, 24, 0, 0, c3, cB); }                                        \
    if (!(GUARDED) || (c2>=0 && c2<NCH)){                                      \
        R_STEPN(2,  0, 0, 1, c2, cA); }                                        \
    if (!(GUARDED) || (c3>=0 && c3<NCH)){                                      \
        R_STEPN(3, 24, 0, 1, c3, cB); }                                        \
    if (!(GUARDED) || (cl>=0 && cl<NCH)){                                      \
        const int bl=cl&1;                                                     \
        G2T(8, W_L4B, (&s_hh[3][bl][0][0]), (&s_hh[3][bl][1][0]),              \
            (&s_xg[bl][4][0][0]), (&s_xg[bl][4][1][0]), 128, b0,b1); }         \
}while(0)

#define BODY_W2(GUARDED) do{                                                   \
    if (!(GUARDED) || (k < NCH)) STAGE_X();                                    \
    const int c4=k-10, cg0=k-1, cg2=k-5;                                       \
    if (!(GUARDED) || (c4>=0 && c4<NCH)){                                      \
        R_STEPN(4, 0, 1, 0, c4, cA); }                                         \
    if (!(GUARDED) || (cg0>=0 && cg0<NCH)){                                    \
        const int bg=cg0&1;                                                    \
        G4T(6, W_L0, (&s_x[bg][0][0]), (&s_x[bg][1][0]),                       \
            (&s_xg[bg][0][0][0]), (&s_xg[bg][0][1][0]), b0,b1,b2,b3); }        \
    if (!(GUARDED) || (c4>=0 && c4<NCH)){                                      \
        R_STEPN(4, 0, 1, 1, c4, cA); }                                         \
    if (!(GUARDED) || (cg2>=0 && cg2<NCH)){                                    \
        const int bg=cg2&1;                                                    \
        G2T(8, W_L2L, (&s_hh[1][bg][0][0]), (&s_hh[1][bg][1][0]),              \
            (&s_xg[bg][2][0][0]), (&s_xg[bg][2][1][0]), 128, b4,b5); }         \
}while(0)

#define BODY_W3(GUARDED) do{                                                   \
    const int cg1=k-3, cg2=k-5, cg3=k-7;                                       \
    if (!(GUARDED) || (cg1>=0 && cg1<NCH)){                                    \
        const int bg=cg1&1;                                                    \
        G4T(8, W_L1, (&s_hh[0][bg][0][0]), (&s_hh[0][bg][1][0]),               \
            (&s_xg[bg][1][0][0]), (&s_xg[bg][1][1][0]), b0,b1,b2,b3); }        \
    if (!(GUARDED) || (cg2>=0 && cg2<NCH)){                                    \
        const int bg=cg2&1;                                                    \
        G2T(8, W_L2R, (&s_hh[1][bg][0][0]), (&s_hh[1][bg][1][0]),              \
            (&s_xg[bg][2][0][0]), (&s_xg[bg][2][1][0]), 0, b4,b5); }           \
    if (!(GUARDED) || (cg3>=0 && cg3<NCH)){                                    \
        const int bg=cg3&1;                                                    \
        G4T(8, W_L3, (&s_hh[2][bg][0][0]), (&s_hh[2][bg][1][0]),               \
            (&s_xg[bg][3][0][0]), (&s_xg[bg][3][1][0]), b6,b7,b8,b9); }        \
}while(0)

    // ================= supercycle loop =================
    for (int k=0; k<KMAX; ++k){
        if (k >= 10 && k < NCH){
            // ---------- FAST PATH: all pieces valid, no guards ----------
            if      (wave == 0) BODY_W0(0);
            else if (wave == 1) BODY_W1(0);
            else if (wave == 2) BODY_W2(0);
            else                BODY_W3(0);
        } else {
            // ---------- SLOW PATH: prologue/epilogue, guarded ----------
            if      (wave == 0) BODY_W0(1);
            else if (wave == 1) BODY_W1(1);
            else if (wave == 2) BODY_W2(1);
            else                BODY_W3(1);
        }
        __syncthreads();
    }
}

// MLP head: features = gelu(last @ Wl^T + bl); out = relu(features @ Wo^T + bo)
// d_out layout: out[256*4] first, then features[256*128].
__global__ __launch_bounds__(128)
void head_kernel(const float* __restrict__ h_last,  // [256, 64]
                 const float* __restrict__ Wl,      // [128, 64]
                 const float* __restrict__ bl,      // [128]
                 const float* __restrict__ Wo,      // [4, 128]
                 const float* __restrict__ bo,      // [4]
                 float* __restrict__ d_out)
{
    __shared__ float s_last[HID];
    __shared__ float s_feat[128];
    const int s = blockIdx.x;
    const int j = threadIdx.x;

    if (j < HID) s_last[j] = h_last[(size_t)s * HID + j];
    __syncthreads();

    float acc = bl[j];
#pragma unroll
    for (int k = 0; k < HID; ++k)
        acc = fmaf(s_last[k], Wl[j * HID + k], acc);
    float f = 0.5f * acc * (1.0f + erff(acc * 0.70710678118654752440f));
    d_out[256 * 4 + s * 128 + j] = f;
    s_feat[j] = f;
    __syncthreads();

    if (j < 4) {
        float a = bo[j];
#pragma unroll
        for (int k = 0; k < 128; ++k)
            a = fmaf(s_feat[k], Wo[j * 128 + k], a);
        d_out[s * 4 + j] = fmaxf(a, 0.0f);
    }
}

extern "C" void kernel_launch(void* const* d_in, const int* in_sizes, int n_in,
                              void* d_out, int out_size, void* d_ws, size_t ws_size,
                              hipStream_t stream)
{
    const float* x         = (const float*)d_in[0];  // [256, 2048, 45]
    const float* W_ih0     = (const float*)d_in[1];  // [256, 45]
    const float* W_ih_rest = (const float*)d_in[2];  // [4, 256, 64]
    const float* W_hh      = (const float*)d_in[3];  // [5, 256, 64]
    const float* b_ih      = (const float*)d_in[4];  // [5, 256]
    const float* b_hh      = (const float*)d_in[5];  // [5, 256]
    const float* Wl        = (const float*)d_in[6];  // [128, 64]
    const float* bl        = (const float*)d_in[7];  // [128]
    const float* Wo        = (const float*)d_in[8];  // [4, 128]
    const float* bo        = (const float*)d_in[9];  // [4]

    float* h_last = (float*)d_ws;   // [256, 64] fp32

    lstm_pipe4<<<256, 256, 0, stream>>>(
        x, W_ih0, W_ih_rest, W_hh, b_ih, b_hh, h_last);
    head_kernel<<<256, 128, 0, stream>>>(h_last, Wl, bl, Wo, bo, (float*)d_out);
}